// Round 1
// baseline (6998.662 us; speedup 1.0000x reference)
//
#include <hip/hip_runtime.h>
#include <math.h>

// Problem constants
constexpr int kT = 2048;   // tokens (B*S)
constexpr int kH = 1024;   // hidden
constexpr int kI = 4096;   // ffn inner
constexpr int kE = 8;      // experts
constexpr int kV = 32000;  // vocab
constexpr int kL = 2;      // layers

// ---------------- small per-token kernels ----------------

__global__ void gather_k(const int* __restrict__ ids, const float* __restrict__ emb,
                         float* __restrict__ h) {
  int t = blockIdx.x;
  int id = ids[t];
  const float4* src = (const float4*)(emb + (size_t)id * kH);
  float4* dst = (float4*)(h + (size_t)t * kH);
  dst[threadIdx.x] = src[threadIdx.x];  // 256 threads * float4 = 1024 floats
}

__global__ void router_k(const float* __restrict__ h, const float* __restrict__ rw,
                         const float* __restrict__ rb, float* __restrict__ logits) {
  int t = blockIdx.x;
  int lg = threadIdx.x & 31;   // lane within 32-thread group
  int e = threadIdx.x >> 5;    // expert 0..7
  const float* hr = h + (size_t)t * kH;
  const float* wr = rw + (size_t)e * kH;
  float p = 0.f;
  for (int k = lg * 4; k < kH; k += 128) {
    float4 a = *(const float4*)(hr + k);
    float4 b = *(const float4*)(wr + k);
    p += a.x * b.x + a.y * b.y + a.z * b.z + a.w * b.w;
  }
  for (int o = 16; o > 0; o >>= 1) p += __shfl_down(p, o, 32);
  if (lg == 0) logits[t * kE + e] = p + rb[e];
}

__global__ void topk_k(const float* __restrict__ logits, int* __restrict__ sel,
                       float* __restrict__ w_sum, int* __restrict__ cnt) {
  int t = blockIdx.x * blockDim.x + threadIdx.x;
  if (t >= kT) return;
  float v[8];
#pragma unroll
  for (int e = 0; e < 8; e++) v[e] = logits[t * 8 + e];
  // jax.lax.top_k tie-break: lowest index first -> strict '>' keeps first max
  int e1 = 0; float v1 = v[0];
#pragma unroll
  for (int e = 1; e < 8; e++) if (v[e] > v1) { v1 = v[e]; e1 = e; }
  int e2 = -1; float v2 = -3.4e38f;
#pragma unroll
  for (int e = 0; e < 8; e++) if (e != e1 && v[e] > v2) { v2 = v[e]; e2 = e; }
  // softmax over [v1, v2] (v1 >= v2)
  float z = expf(v2 - v1);
  float w1 = 1.f / (1.f + z);
  float w2 = z * w1;
  sel[t * 2] = e1;
  sel[t * 2 + 1] = e2;
  atomicAdd(&w_sum[e1], w1);
  atomicAdd(&w_sum[e2], w2);
  atomicAdd(&cnt[e1], 1);
  atomicAdd(&cnt[e2], 1);
}

__global__ void finalize_k(const int* __restrict__ cnt, const float* __restrict__ w_sum,
                           float* __restrict__ scal, int* __restrict__ off,
                           int* __restrict__ fill, float* __restrict__ aux) {
  if (threadIdx.x == 0) {
    int o = 0;
    float a = 0.f;
    for (int e = 0; e < 8; e++) {
      off[e] = o;
      o += cnt[e];
      fill[e] = 0;
      int c = cnt[e];
      scal[e] = c > 0 ? w_sum[e] / (float)c : 0.f;
      float d = (float)c - 256.f;  // T/E = 256
      a += d * d;
    }
    aux[0] += 0.01f * (a * 0.125f);  // mean over 8 experts
  }
}

__global__ void scatter_k(const int* __restrict__ sel, const int* __restrict__ off,
                          int* __restrict__ fill, int* __restrict__ list) {
  int t = blockIdx.x * blockDim.x + threadIdx.x;
  if (t >= kT) return;
#pragma unroll
  for (int s = 0; s < 2; s++) {
    int e = sel[t * 2 + s];
    int p = atomicAdd(&fill[e], 1);
    list[off[e] + p] = t;
  }
}

__global__ void ln_k(float* __restrict__ h, const float* __restrict__ x,
                     const float* __restrict__ g, const float* __restrict__ b) {
  int t = blockIdx.x;
  const float* xr = x + (size_t)t * kH;
  int k = threadIdx.x * 4;
  float4 v = *(const float4*)(xr + k);
  float s = v.x + v.y + v.z + v.w;
  float sq = v.x * v.x + v.y * v.y + v.z * v.z + v.w * v.w;
  for (int o = 32; o > 0; o >>= 1) {
    s += __shfl_down(s, o);
    sq += __shfl_down(sq, o);
  }
  __shared__ float ss[4], sqs[4];
  int wave = threadIdx.x >> 6, lane = threadIdx.x & 63;
  if (lane == 0) { ss[wave] = s; sqs[wave] = sq; }
  __syncthreads();
  __shared__ float mu, inv;
  if (threadIdx.x == 0) {
    float st = ss[0] + ss[1] + ss[2] + ss[3];
    float sqt = sqs[0] + sqs[1] + sqs[2] + sqs[3];
    float m = st / (float)kH;
    float var = sqt / (float)kH - m * m;
    mu = m;
    inv = 1.f / sqrtf(var + 1e-5f);
  }
  __syncthreads();
  float4 gg = *(const float4*)(g + k);
  float4 bb = *(const float4*)(b + k);
  float4 o;
  o.x = (v.x - mu) * inv * gg.x + bb.x;
  o.y = (v.y - mu) * inv * gg.y + bb.y;
  o.z = (v.z - mu) * inv * gg.z + bb.z;
  o.w = (v.w - mu) * inv * gg.w + bb.w;
  *(float4*)(h + (size_t)t * kH + k) = o;
}

__global__ void aux_write_k(float* __restrict__ out, const float* __restrict__ aux) {
  out[(size_t)kT * kV] = aux[0];
}

// ---------------- f32 tiled GEMM: C[m,n] = sum_k A[m,k]*B[n,k] (+epilogue) ----------------
// MODE 0: fc1  (A rows gathered via token list; epilogue = bias + exact GELU -> a_buf)
// MODE 1: fc2  (A rows = compact a_buf rows; epilogue = scal[e]*(acc+bias) atomicAdd-scatter)
// MODE 2: head (dense; epilogue = bias, store to d_out)
template <int MODE>
__launch_bounds__(256)
__global__ void gemm_k(const float* __restrict__ Abase, int ldA,
                       const float* __restrict__ Bbase,
                       const float* __restrict__ bias,
                       float* __restrict__ Cout,
                       const int* __restrict__ list,
                       const int* __restrict__ off,
                       const int* __restrict__ cnt,
                       const float* __restrict__ scal,
                       int N, int Kd) {
  const int e = (MODE == 2) ? 0 : blockIdx.z;
  int M;
  if constexpr (MODE == 2) M = kT; else M = cnt[e];
  const int m0 = blockIdx.x * 128;
  if (m0 >= M) return;  // uniform per block
  const int n0 = blockIdx.y * 128;
  int roff = 0;
  if constexpr (MODE != 2) roff = off[e];
  const float* Bp = Bbase + (size_t)e * (size_t)N * (size_t)Kd;
  const float* be = bias + (size_t)e * (size_t)N;

  __shared__ float As[16][132];
  __shared__ float Bs[16][132];

  const int tid = threadIdx.x;
  const float* aptr[2];
  const float* bptr[2];
#pragma unroll
  for (int q = 0; q < 2; q++) {
    int s = tid + q * 256;
    int row = s >> 2, kq = (s & 3) * 4;
    int r = m0 + row;
    int rc = r < M ? r : M - 1;  // clamp OOB rows to a valid address
    size_t asrc;
    if constexpr (MODE == 0) asrc = (size_t)list[roff + rc] * (size_t)ldA;
    else if constexpr (MODE == 1) asrc = (size_t)(roff + rc) * (size_t)ldA;
    else asrc = (size_t)rc * (size_t)ldA;
    aptr[q] = Abase + asrc + kq;
    bptr[q] = Bp + (size_t)(n0 + row) * (size_t)Kd + kq;
  }

  float acc[8][8] = {};
  const int tx = tid & 15, ty = tid >> 4;

  for (int k0 = 0; k0 < Kd; k0 += 16) {
#pragma unroll
    for (int q = 0; q < 2; q++) {
      int s = tid + q * 256;
      int row = s >> 2, kq = (s & 3) * 4;
      float4 va = *(const float4*)(aptr[q] + k0);
      float4 vb = *(const float4*)(bptr[q] + k0);
      As[kq + 0][row] = va.x; As[kq + 1][row] = va.y;
      As[kq + 2][row] = va.z; As[kq + 3][row] = va.w;
      Bs[kq + 0][row] = vb.x; Bs[kq + 1][row] = vb.y;
      Bs[kq + 2][row] = vb.z; Bs[kq + 3][row] = vb.w;
    }
    __syncthreads();
#pragma unroll
    for (int k = 0; k < 16; k++) {
      float a[8], b[8];
      *(float4*)&a[0] = *(const float4*)&As[k][ty * 8];
      *(float4*)&a[4] = *(const float4*)&As[k][ty * 8 + 4];
      *(float4*)&b[0] = *(const float4*)&Bs[k][tx * 8];
      *(float4*)&b[4] = *(const float4*)&Bs[k][tx * 8 + 4];
#pragma unroll
      for (int i = 0; i < 8; i++)
#pragma unroll
        for (int j = 0; j < 8; j++)
          acc[i][j] = fmaf(a[i], b[j], acc[i][j]);
    }
    __syncthreads();
  }

#pragma unroll
  for (int i = 0; i < 8; i++) {
    int gm = m0 + ty * 8 + i;
    if (gm >= M) continue;
    if constexpr (MODE == 0) {
      float* orow = Cout + (size_t)(roff + gm) * (size_t)N + n0 + tx * 8;
#pragma unroll
      for (int j = 0; j < 8; j++) {
        float x = acc[i][j] + be[n0 + tx * 8 + j];
        orow[j] = 0.5f * x * (1.f + erff(x * 0.70710678118654752f));
      }
    } else if constexpr (MODE == 1) {
      int t = list[roff + gm];
      float se = scal[e];
      float* orow = Cout + (size_t)t * (size_t)N + n0 + tx * 8;
#pragma unroll
      for (int j = 0; j < 8; j++)
        atomicAdd(&orow[j], se * (acc[i][j] + be[n0 + tx * 8 + j]));
    } else {
      float* orow = Cout + (size_t)gm * (size_t)N + n0 + tx * 8;
      float4 o0, o1;
      o0.x = acc[i][0] + be[n0 + tx * 8 + 0];
      o0.y = acc[i][1] + be[n0 + tx * 8 + 1];
      o0.z = acc[i][2] + be[n0 + tx * 8 + 2];
      o0.w = acc[i][3] + be[n0 + tx * 8 + 3];
      o1.x = acc[i][4] + be[n0 + tx * 8 + 4];
      o1.y = acc[i][5] + be[n0 + tx * 8 + 5];
      o1.z = acc[i][6] + be[n0 + tx * 8 + 6];
      o1.w = acc[i][7] + be[n0 + tx * 8 + 7];
      *(float4*)&orow[0] = o0;
      *(float4*)&orow[4] = o1;
    }
  }
}

// ---------------- launch ----------------

extern "C" void kernel_launch(void* const* d_in, const int* in_sizes, int n_in,
                              void* d_out, int out_size, void* d_ws, size_t ws_size,
                              hipStream_t stream) {
  (void)in_sizes; (void)n_in; (void)out_size; (void)ws_size;
  const int* ids = (const int*)d_in[0];
  const float* emb = (const float*)d_in[1];
  const float* router_w = (const float*)d_in[2];
  const float* router_b = (const float*)d_in[3];
  const float* fc1_w = (const float*)d_in[4];
  const float* fc1_b = (const float*)d_in[5];
  const float* fc2_w = (const float*)d_in[6];
  const float* fc2_b = (const float*)d_in[7];
  const float* ln_g = (const float*)d_in[8];
  const float* ln_b = (const float*)d_in[9];
  const float* head_w = (const float*)d_in[10];
  const float* head_b = (const float*)d_in[11];
  float* out = (float*)d_out;

  // workspace layout (floats, then ints); ~17 MB total
  float* ws_f = (float*)d_ws;
  float* h       = ws_f;                          // kT*kH
  float* out_acc = h + (size_t)kT * kH;           // kT*kH
  float* logits  = out_acc + (size_t)kT * kH;     // kT*kE
  float* w_sum   = logits + (size_t)kT * kE;      // kE
  float* scal    = w_sum + kE;                    // kE
  float* aux     = scal + kE;                     // 1
  int* sel  = (int*)(aux + 1);                    // kT*2
  int* cnt  = sel + 2 * kT;                       // kE
  int* off  = cnt + kE;                           // kE
  int* fill = off + kE;                           // kE
  int* list = fill + kE;                          // kT*2

  // fc1 activation buffer (4096 x kI f32 = 64 MB) lives in d_out's logits area;
  // the head GEMM fully overwrites d_out afterwards.
  float* a_buf = out;

  hipMemsetAsync(aux, 0, sizeof(float), stream);
  gather_k<<<kT, 256, 0, stream>>>(ids, emb, h);

  for (int l = 0; l < kL; l++) {
    hipMemsetAsync(w_sum, 0, kE * sizeof(float), stream);
    hipMemsetAsync(cnt, 0, kE * sizeof(int), stream);
    router_k<<<kT, 256, 0, stream>>>(h, router_w + (size_t)l * kE * kH,
                                     router_b + (size_t)l * kE, logits);
    topk_k<<<kT / 256, 256, 0, stream>>>(logits, sel, w_sum, cnt);
    finalize_k<<<1, 64, 0, stream>>>(cnt, w_sum, scal, off, fill, aux);
    scatter_k<<<kT / 256, 256, 0, stream>>>(sel, off, fill, list);
    hipMemsetAsync(out_acc, 0, (size_t)kT * kH * sizeof(float), stream);

    // fc1 + GELU: [cnt_e, kH] x [kI, kH]^T -> a_buf (compact rows)
    gemm_k<0><<<dim3(kT / 128, kI / 128, kE), 256, 0, stream>>>(
        h, kH, fc1_w + (size_t)l * kE * kI * kH, fc1_b + (size_t)l * kE * kI,
        a_buf, list, off, cnt, scal, kI, kH);
    // fc2 + bias, *scal, scatter-add: [cnt_e, kI] x [kH, kI]^T -> out_acc
    gemm_k<1><<<dim3(kT / 128, kH / 128, kE), 256, 0, stream>>>(
        a_buf, kI, fc2_w + (size_t)l * kE * kH * kI, fc2_b + (size_t)l * kE * kH,
        out_acc, list, off, cnt, scal, kH, kI);

    ln_k<<<kT, 256, 0, stream>>>(h, out_acc, ln_g + (size_t)l * kH, ln_b + (size_t)l * kH);
  }

  // head: [kT, kH] x [kV, kH]^T + head_b -> d_out (overwrites a_buf region)
  gemm_k<2><<<dim3(kT / 128, kV / 128, 1), 256, 0, stream>>>(
      h, kH, head_w, head_b, out, nullptr, nullptr, nullptr, nullptr, kV, kH);

  aux_write_k<<<1, 1, 0, stream>>>(out, aux);
}

// Round 2
// 3858.738 us; speedup vs baseline: 1.8137x; 1.8137x over previous
//
#include <hip/hip_runtime.h>
#include <math.h>

// Problem constants
constexpr int kT = 2048;   // tokens (B*S)
constexpr int kH = 1024;   // hidden
constexpr int kI = 4096;   // ffn inner
constexpr int kE = 8;      // experts
constexpr int kV = 32000;  // vocab
constexpr int kL = 2;      // layers

typedef __attribute__((ext_vector_type(4))) float f32x4;
typedef __attribute__((ext_vector_type(8))) short bf16x8;

__device__ inline unsigned short f2bf(float x) {
  union { float f; unsigned u; } c; c.f = x;
  unsigned u = c.u;
  u += 0x7FFFu + ((u >> 16) & 1u);  // RNE
  return (unsigned short)(u >> 16);
}

// ---------------- small per-token kernels ----------------

__global__ void gather_k(const int* __restrict__ ids, const float* __restrict__ emb,
                         float* __restrict__ h) {
  int t = blockIdx.x;
  int id = ids[t];
  const float4* src = (const float4*)(emb + (size_t)id * kH);
  float4* dst = (float4*)(h + (size_t)t * kH);
  dst[threadIdx.x] = src[threadIdx.x];
}

__global__ void router_k(const float* __restrict__ h, const float* __restrict__ rw,
                         const float* __restrict__ rb, float* __restrict__ logits) {
  int t = blockIdx.x;
  int lg = threadIdx.x & 31;
  int e = threadIdx.x >> 5;
  const float* hr = h + (size_t)t * kH;
  const float* wr = rw + (size_t)e * kH;
  float p = 0.f;
  for (int k = lg * 4; k < kH; k += 128) {
    float4 a = *(const float4*)(hr + k);
    float4 b = *(const float4*)(wr + k);
    p += a.x * b.x + a.y * b.y + a.z * b.z + a.w * b.w;
  }
  for (int o = 16; o > 0; o >>= 1) p += __shfl_down(p, o, 32);
  if (lg == 0) logits[t * kE + e] = p + rb[e];
}

__global__ void topk_k(const float* __restrict__ logits, int* __restrict__ sel,
                       float* __restrict__ w_sum, int* __restrict__ cnt) {
  int t = blockIdx.x * blockDim.x + threadIdx.x;
  if (t >= kT) return;
  float v[8];
#pragma unroll
  for (int e = 0; e < 8; e++) v[e] = logits[t * 8 + e];
  int e1 = 0; float v1 = v[0];
#pragma unroll
  for (int e = 1; e < 8; e++) if (v[e] > v1) { v1 = v[e]; e1 = e; }
  int e2 = -1; float v2 = -3.4e38f;
#pragma unroll
  for (int e = 0; e < 8; e++) if (e != e1 && v[e] > v2) { v2 = v[e]; e2 = e; }
  float z = expf(v2 - v1);
  float w1 = 1.f / (1.f + z);
  float w2 = z * w1;
  sel[t * 2] = e1;
  sel[t * 2 + 1] = e2;
  atomicAdd(&w_sum[e1], w1);
  atomicAdd(&w_sum[e2], w2);
  atomicAdd(&cnt[e1], 1);
  atomicAdd(&cnt[e2], 1);
}

__global__ void finalize_k(const int* __restrict__ cnt, const float* __restrict__ w_sum,
                           float* __restrict__ scal, int* __restrict__ off,
                           int* __restrict__ fill, float* __restrict__ aux) {
  if (threadIdx.x == 0) {
    int o = 0;
    float a = 0.f;
    for (int e = 0; e < 8; e++) {
      off[e] = o;
      o += cnt[e];
      fill[e] = 0;
      int c = cnt[e];
      scal[e] = c > 0 ? w_sum[e] / (float)c : 0.f;
      float d = (float)c - 256.f;
      a += d * d;
    }
    aux[0] += 0.01f * (a * 0.125f);
  }
}

__global__ void scatter_k(const int* __restrict__ sel, const int* __restrict__ off,
                          int* __restrict__ fill, int* __restrict__ list) {
  int t = blockIdx.x * blockDim.x + threadIdx.x;
  if (t >= kT) return;
#pragma unroll
  for (int s = 0; s < 2; s++) {
    int e = sel[t * 2 + s];
    int p = atomicAdd(&fill[e], 1);
    list[off[e] + p] = t;
  }
}

__global__ void ln_k(float* __restrict__ h, const float* __restrict__ x,
                     const float* __restrict__ g, const float* __restrict__ b) {
  int t = blockIdx.x;
  const float* xr = x + (size_t)t * kH;
  int k = threadIdx.x * 4;
  float4 v = *(const float4*)(xr + k);
  float s = v.x + v.y + v.z + v.w;
  float sq = v.x * v.x + v.y * v.y + v.z * v.z + v.w * v.w;
  for (int o = 32; o > 0; o >>= 1) {
    s += __shfl_down(s, o);
    sq += __shfl_down(sq, o);
  }
  __shared__ float ss[4], sqs[4];
  int wave = threadIdx.x >> 6, lane = threadIdx.x & 63;
  if (lane == 0) { ss[wave] = s; sqs[wave] = sq; }
  __syncthreads();
  __shared__ float mu, inv;
  if (threadIdx.x == 0) {
    float st = ss[0] + ss[1] + ss[2] + ss[3];
    float sqt = sqs[0] + sqs[1] + sqs[2] + sqs[3];
    float m = st / (float)kH;
    float var = sqt / (float)kH - m * m;
    mu = m;
    inv = 1.f / sqrtf(var + 1e-5f);
  }
  __syncthreads();
  float4 gg = *(const float4*)(g + k);
  float4 bb = *(const float4*)(b + k);
  float4 o;
  o.x = (v.x - mu) * inv * gg.x + bb.x;
  o.y = (v.y - mu) * inv * gg.y + bb.y;
  o.z = (v.z - mu) * inv * gg.z + bb.z;
  o.w = (v.w - mu) * inv * gg.w + bb.w;
  *(float4*)(h + (size_t)t * kH + k) = o;
}

__global__ void aux_write_k(float* __restrict__ out, const float* __restrict__ aux) {
  out[(size_t)kT * kV] = aux[0];
}

// f32 -> bf16 (RNE), 8 elems/thread; n must be a multiple of 2048
__global__ void cvt_k(const float* __restrict__ src, unsigned short* __restrict__ dst, long n) {
  long i = ((long)blockIdx.x * 256 + threadIdx.x) * 8;
  if (i >= n) return;
  float4 a = *(const float4*)(src + i);
  float4 b = *(const float4*)(src + i + 4);
  uint4 pk;
  pk.x = (unsigned)f2bf(a.x) | ((unsigned)f2bf(a.y) << 16);
  pk.y = (unsigned)f2bf(a.z) | ((unsigned)f2bf(a.w) << 16);
  pk.z = (unsigned)f2bf(b.x) | ((unsigned)f2bf(b.y) << 16);
  pk.w = (unsigned)f2bf(b.z) | ((unsigned)f2bf(b.w) << 16);
  *(uint4*)(dst + i) = pk;
}

// ---------------- f32 tiled GEMM (layer-1 FFN + head fallback) ----------------
// MODE 0: fc1 (gather rows, GELU -> f32 a_buf)
// MODE 1: fc2 (compact rows, split-K=4, scal*(acc+bias) atomicAdd scatter)
// MODE 2: head (dense, +bias -> d_out)
template <int MODE>
__launch_bounds__(256)
__global__ void gemm_k(const float* __restrict__ Abase, int ldA,
                       const float* __restrict__ Bbase,
                       const float* __restrict__ bias,
                       float* __restrict__ Cout,
                       const int* __restrict__ list,
                       const int* __restrict__ off,
                       const int* __restrict__ cnt,
                       const float* __restrict__ scal,
                       int N, int Kd) {
  const int e = (MODE == 2) ? 0 : blockIdx.z;
  int M;
  if constexpr (MODE == 2) M = kT; else M = cnt[e];
  const int m0 = blockIdx.x * 128;
  if (m0 >= M) return;
  int nb = blockIdx.y, kc = 0;
  if constexpr (MODE == 1) { nb = blockIdx.y >> 2; kc = blockIdx.y & 3; }
  const int n0 = nb * 128;
  int roff = 0;
  if constexpr (MODE != 2) roff = off[e];
  const float* Bp = Bbase + (size_t)e * (size_t)N * (size_t)Kd;
  const float* be = bias + (size_t)e * (size_t)N;
  const int kBeg = (MODE == 1) ? kc * (Kd >> 2) : 0;
  const int kEnd = (MODE == 1) ? kBeg + (Kd >> 2) : Kd;

  __shared__ float As[16][132];
  __shared__ float Bs[16][132];

  const int tid = threadIdx.x;
  const float* aptr[2];
  const float* bptr[2];
#pragma unroll
  for (int q = 0; q < 2; q++) {
    int s = tid + q * 256;
    int row = s >> 2, kq = (s & 3) * 4;
    int r = m0 + row;
    int rc = r < M ? r : M - 1;
    size_t asrc;
    if constexpr (MODE == 0) asrc = (size_t)list[roff + rc] * (size_t)ldA;
    else if constexpr (MODE == 1) asrc = (size_t)(roff + rc) * (size_t)ldA;
    else asrc = (size_t)rc * (size_t)ldA;
    aptr[q] = Abase + asrc + kq;
    bptr[q] = Bp + (size_t)(n0 + row) * (size_t)Kd + kq;
  }

  float acc[8][8] = {};
  const int tx = tid & 15, ty = tid >> 4;

  for (int k0 = kBeg; k0 < kEnd; k0 += 16) {
#pragma unroll
    for (int q = 0; q < 2; q++) {
      int s = tid + q * 256;
      int row = s >> 2, kq = (s & 3) * 4;
      float4 va = *(const float4*)(aptr[q] + k0);
      float4 vb = *(const float4*)(bptr[q] + k0);
      As[kq + 0][row] = va.x; As[kq + 1][row] = va.y;
      As[kq + 2][row] = va.z; As[kq + 3][row] = va.w;
      Bs[kq + 0][row] = vb.x; Bs[kq + 1][row] = vb.y;
      Bs[kq + 2][row] = vb.z; Bs[kq + 3][row] = vb.w;
    }
    __syncthreads();
#pragma unroll
    for (int k = 0; k < 16; k++) {
      float a[8], b[8];
      *(float4*)&a[0] = *(const float4*)&As[k][ty * 8];
      *(float4*)&a[4] = *(const float4*)&As[k][ty * 8 + 4];
      *(float4*)&b[0] = *(const float4*)&Bs[k][tx * 8];
      *(float4*)&b[4] = *(const float4*)&Bs[k][tx * 8 + 4];
#pragma unroll
      for (int i = 0; i < 8; i++)
#pragma unroll
        for (int j = 0; j < 8; j++)
          acc[i][j] = fmaf(a[i], b[j], acc[i][j]);
    }
    __syncthreads();
  }

#pragma unroll
  for (int i = 0; i < 8; i++) {
    int gm = m0 + ty * 8 + i;
    if (gm >= M) continue;
    if constexpr (MODE == 0) {
      float* orow = Cout + (size_t)(roff + gm) * (size_t)N + n0 + tx * 8;
#pragma unroll
      for (int j = 0; j < 8; j++) {
        float x = acc[i][j] + be[n0 + tx * 8 + j];
        orow[j] = 0.5f * x * (1.f + erff(x * 0.70710678118654752f));
      }
    } else if constexpr (MODE == 1) {
      int t = list[roff + gm];
      float se = scal[e];
      float* orow = Cout + (size_t)t * (size_t)N + n0 + tx * 8;
#pragma unroll
      for (int j = 0; j < 8; j++) {
        float bb = (kc == 0) ? be[n0 + tx * 8 + j] : 0.f;
        atomicAdd(&orow[j], se * (acc[i][j] + bb));
      }
    } else {
      float* orow = Cout + (size_t)gm * (size_t)N + n0 + tx * 8;
      float4 o0, o1;
      o0.x = acc[i][0] + be[n0 + tx * 8 + 0];
      o0.y = acc[i][1] + be[n0 + tx * 8 + 1];
      o0.z = acc[i][2] + be[n0 + tx * 8 + 2];
      o0.w = acc[i][3] + be[n0 + tx * 8 + 3];
      o1.x = acc[i][4] + be[n0 + tx * 8 + 4];
      o1.y = acc[i][5] + be[n0 + tx * 8 + 5];
      o1.z = acc[i][6] + be[n0 + tx * 8 + 6];
      o1.w = acc[i][7] + be[n0 + tx * 8 + 7];
      *(float4*)&orow[0] = o0;
      *(float4*)&orow[4] = o1;
    }
  }
}

// ---------------- bf16 MFMA GEMM (m97 structure): C[m,n] = sum_k A[m,k]*B[n,k] ----------------
// 128x128 tile, BK=64, 256 threads = 4 waves (2x2), wave = 64x64 = 4x4 16x16x32 frags.
// A, B staged via global_load_lds(16B), linear LDS [128][64] bf16.
// MODE 0: fc1-l2 (A rows via list gather, GELU -> bf16 a_buf)
// MODE 1: fc2-l2 (A = compact a_buf, split-K=4, scal*(acc+bias) atomicAdd scatter)
// MODE 2: head  (dense, +bias -> f32 out)
template <int MODE>
__launch_bounds__(256)
__global__ void mgemm_k(const unsigned short* __restrict__ Abase, int ldA,
                        const unsigned short* __restrict__ Bbase,
                        const float* __restrict__ bias,
                        float* __restrict__ Cout,
                        unsigned short* __restrict__ Cbf,
                        const int* __restrict__ list,
                        const int* __restrict__ off,
                        const int* __restrict__ cnt,
                        const float* __restrict__ scal,
                        int N, int Kd) {
  const int e = (MODE == 2) ? 0 : blockIdx.z;
  int M;
  if constexpr (MODE == 2) M = kT; else M = cnt[e];
  const int m0 = blockIdx.x * 128;
  if (m0 >= M) return;
  int nb = blockIdx.y, kc = 0;
  if constexpr (MODE == 1) { nb = blockIdx.y >> 2; kc = blockIdx.y & 3; }
  const int n0 = nb * 128;
  int roff = 0;
  if constexpr (MODE != 2) roff = off[e];
  const unsigned short* Bp = Bbase + (size_t)e * (size_t)N * (size_t)Kd;
  const float* be = bias + (size_t)e * (size_t)N;
  const int kBeg = (MODE == 1) ? kc * (Kd >> 2) : 0;
  const int kEnd = (MODE == 1) ? kBeg + (Kd >> 2) : Kd;

  __shared__ unsigned short As[128 * 64];
  __shared__ unsigned short Bs[128 * 64];

  const int tid = threadIdx.x, w = tid >> 6, l = tid & 63;

  // staging source pointers: lane covers row r = w*8 + i*32 + (l>>3), col (l&7)*8
  const unsigned short* asrc[4];
  const unsigned short* bsrc[4];
#pragma unroll
  for (int i = 0; i < 4; i++) {
    int r = w * 8 + i * 32 + (l >> 3);
    int gr = m0 + r; if (gr > M - 1) gr = M - 1;
    long grow;
    if constexpr (MODE == 0) grow = list[roff + gr];
    else if constexpr (MODE == 1) grow = roff + gr;
    else grow = gr;
    asrc[i] = Abase + grow * (long)ldA + (l & 7) * 8;
    bsrc[i] = Bp + (size_t)(n0 + r) * (size_t)Kd + (l & 7) * 8;
  }

  f32x4 acc[4][4] = {};
  const int wm = w >> 1, wn = w & 1;
  const int fr = l & 15, fk = (l >> 4) * 8;

  for (int k0 = kBeg; k0 < kEnd; k0 += 64) {
#pragma unroll
    for (int i = 0; i < 4; i++) {
      __builtin_amdgcn_global_load_lds(
          (const __attribute__((address_space(1))) unsigned int*)(const void*)(asrc[i] + k0),
          (__attribute__((address_space(3))) unsigned int*)(void*)(As + w * 512 + i * 2048),
          16, 0, 0);
      __builtin_amdgcn_global_load_lds(
          (const __attribute__((address_space(1))) unsigned int*)(const void*)(bsrc[i] + k0),
          (__attribute__((address_space(3))) unsigned int*)(void*)(Bs + w * 512 + i * 2048),
          16, 0, 0);
    }
    __syncthreads();  // compiler drains vmcnt before s_barrier
#pragma unroll
    for (int ks = 0; ks < 2; ks++) {
      bf16x8 af[4], bfr[4];
#pragma unroll
      for (int am = 0; am < 4; am++)
        af[am] = *(const bf16x8*)(As + (wm * 64 + am * 16 + fr) * 64 + ks * 32 + fk);
#pragma unroll
      for (int bn = 0; bn < 4; bn++)
        bfr[bn] = *(const bf16x8*)(Bs + (wn * 64 + bn * 16 + fr) * 64 + ks * 32 + fk);
#pragma unroll
      for (int am = 0; am < 4; am++)
#pragma unroll
        for (int bn = 0; bn < 4; bn++)
          acc[am][bn] = __builtin_amdgcn_mfma_f32_16x16x32_bf16(af[am], bfr[bn], acc[am][bn], 0, 0, 0);
    }
    __syncthreads();
  }

  // C/D layout: col = lane&15, row = (lane>>4)*4 + j  (m89/m91-verified)
  const int r0 = (l >> 4) * 4, cc = l & 15;
#pragma unroll
  for (int am = 0; am < 4; am++) {
#pragma unroll
    for (int bn = 0; bn < 4; bn++) {
      int gn = n0 + wn * 64 + bn * 16 + cc;
      float bv;
      if constexpr (MODE == 1) bv = (kc == 0) ? be[gn] : 0.f;
      else bv = be[gn];
#pragma unroll
      for (int j = 0; j < 4; j++) {
        int gm = m0 + wm * 64 + am * 16 + r0 + j;
        if (gm >= M) continue;
        float v = acc[am][bn][j] + bv;
        if constexpr (MODE == 0) {
          float g = 0.5f * v * (1.f + erff(v * 0.70710678118654752f));
          Cbf[(size_t)(roff + gm) * (size_t)N + gn] = f2bf(g);
        } else if constexpr (MODE == 1) {
          int t = list[roff + gm];
          atomicAdd(&Cout[(size_t)t * (size_t)N + gn], scal[e] * v);
        } else {
          Cout[(size_t)gm * (size_t)N + gn] = v;
        }
      }
    }
  }
}

// ---------------- launch ----------------

extern "C" void kernel_launch(void* const* d_in, const int* in_sizes, int n_in,
                              void* d_out, int out_size, void* d_ws, size_t ws_size,
                              hipStream_t stream) {
  (void)in_sizes; (void)n_in; (void)out_size;
  const int* ids = (const int*)d_in[0];
  const float* emb = (const float*)d_in[1];
  const float* router_w = (const float*)d_in[2];
  const float* router_b = (const float*)d_in[3];
  const float* fc1_w = (const float*)d_in[4];
  const float* fc1_b = (const float*)d_in[5];
  const float* fc2_w = (const float*)d_in[6];
  const float* fc2_b = (const float*)d_in[7];
  const float* ln_g = (const float*)d_in[8];
  const float* ln_b = (const float*)d_in[9];
  const float* head_w = (const float*)d_in[10];
  const float* head_b = (const float*)d_in[11];
  float* out = (float*)d_out;

  // --- workspace layout ---
  float* ws_f = (float*)d_ws;
  float* h       = ws_f;                          // kT*kH
  float* out_acc = h + (size_t)kT * kH;           // kT*kH
  float* logits  = out_acc + (size_t)kT * kH;     // kT*kE
  float* w_sum   = logits + (size_t)kT * kE;      // kE
  float* scal    = w_sum + kE;                    // kE
  float* aux     = scal + kE;                     // 1
  int* sel  = (int*)(aux + 1);                    // kT*2
  int* cnt  = sel + 2 * kT;                       // kE
  int* off  = cnt + kE;                           // kE
  int* fill = off + kE;                           // kE
  int* list = fill + kE;                          // kT*2
  size_t base_off = (((size_t)((char*)(list + 2 * kT) - (char*)d_ws)) + 15) & ~(size_t)15;

  // --- d_out scratch (all overwritten by head GEMM at the end) ---
  unsigned short* a_bf  = (unsigned short*)d_out;               // 4096*kI bf16 (33.5 MB)
  unsigned short* w1_bf = a_bf + (size_t)4096 * kI;             // kE*kI*kH bf16 (67 MB)
  unsigned short* w2_bf = w1_bf + (size_t)kE * kI * kH;         // kE*kH*kI bf16 (67 MB)
  unsigned short* h_bf_dout = w2_bf + (size_t)kE * kH * kI;     // kT*kH bf16 (4 MB)

  // head_w bf16 must live in ws (it is read while head GEMM writes all of d_out)
  unsigned short* h_bf_ws = (unsigned short*)((char*)d_ws + base_off);
  unsigned short* hw_bf   = h_bf_ws + (size_t)kT * kH;
  size_t ws_need_head = base_off + (size_t)kT * kH * 2 + (size_t)kV * kH * 2;
  bool mfma_head = ws_size >= ws_need_head;
  unsigned short* h_bf = mfma_head ? h_bf_ws : h_bf_dout;

  // f32 a_buf for layer-1 fc1 output (same region as a_bf, sequential use)
  float* a_f32 = out;

  hipMemsetAsync(aux, 0, sizeof(float), stream);
  gather_k<<<kT, 256, 0, stream>>>(ids, emb, h);

  for (int l = 0; l < kL; l++) {
    hipMemsetAsync(w_sum, 0, kE * sizeof(float), stream);
    hipMemsetAsync(cnt, 0, kE * sizeof(int), stream);
    router_k<<<kT, 256, 0, stream>>>(h, router_w + (size_t)l * kE * kH,
                                     router_b + (size_t)l * kE, logits);
    topk_k<<<kT / 256, 256, 0, stream>>>(logits, sel, w_sum, cnt);
    finalize_k<<<1, 64, 0, stream>>>(cnt, w_sum, scal, off, fill, aux);
    scatter_k<<<kT / 256, 256, 0, stream>>>(sel, off, fill, list);
    hipMemsetAsync(out_acc, 0, (size_t)kT * kH * sizeof(float), stream);

    if (l == 0) {
      // layer-1: f32 (routing-critical for layer-2 router)
      gemm_k<0><<<dim3(kT / 128, kI / 128, kE), 256, 0, stream>>>(
          h, kH, fc1_w + (size_t)l * kE * kI * kH, fc1_b + (size_t)l * kE * kI,
          a_f32, list, off, cnt, scal, kI, kH);
      gemm_k<1><<<dim3(kT / 128, (kH / 128) * 4, kE), 256, 0, stream>>>(
          a_f32, kI, fc2_w + (size_t)l * kE * kH * kI, fc2_b + (size_t)l * kE * kH,
          out_acc, list, off, cnt, scal, kH, kI);
    } else {
      // layer-2: bf16 MFMA (downstream of all routing)
      cvt_k<<<(int)(((long)kT * kH) / 2048), 256, 0, stream>>>(h, h_bf, (long)kT * kH);
      cvt_k<<<(int)(((long)kE * kI * kH) / 2048), 256, 0, stream>>>(
          fc1_w + (size_t)l * kE * kI * kH, w1_bf, (long)kE * kI * kH);
      cvt_k<<<(int)(((long)kE * kH * kI) / 2048), 256, 0, stream>>>(
          fc2_w + (size_t)l * kE * kH * kI, w2_bf, (long)kE * kH * kI);
      mgemm_k<0><<<dim3(kT / 128, kI / 128, kE), 256, 0, stream>>>(
          h_bf, kH, w1_bf, fc1_b + (size_t)l * kE * kI,
          nullptr, a_bf, list, off, cnt, scal, kI, kH);
      mgemm_k<1><<<dim3(kT / 128, (kH / 128) * 4, kE), 256, 0, stream>>>(
          a_bf, kI, w2_bf, fc2_b + (size_t)l * kE * kH,
          out_acc, nullptr, list, off, cnt, scal, kH, kI);
    }

    ln_k<<<kT, 256, 0, stream>>>(h, out_acc, ln_g + (size_t)l * kH, ln_b + (size_t)l * kH);
  }

  if (mfma_head) {
    cvt_k<<<(int)(((long)kT * kH) / 2048), 256, 0, stream>>>(h, h_bf_ws, (long)kT * kH);
    cvt_k<<<(int)(((long)kV * kH) / 2048), 256, 0, stream>>>(head_w, hw_bf, (long)kV * kH);
    mgemm_k<2><<<dim3(kT / 128, kV / 128, 1), 256, 0, stream>>>(
        h_bf_ws, kH, hw_bf, head_b, out, nullptr, nullptr, nullptr, nullptr, nullptr, kV, kH);
  } else {
    gemm_k<2><<<dim3(kT / 128, kV / 128, 1), 256, 0, stream>>>(
        h, kH, head_w, head_b, out, nullptr, nullptr, nullptr, nullptr, kV, kH);
  }

  aux_write_k<<<1, 1, 0, stream>>>(out, aux);
}